// Round 5
// baseline (168.225 us; speedup 1.0000x reference)
//
#include <hip/hip_runtime.h>
#include <math.h>

#define BSZ 16
#define NQ 300
#define NT 50
#define K3 51
#define NPRED (BSZ*NQ)     // 4800
#define NTGT  (BSZ*NT)     // 800
#define NC    (NPRED*NTGT) // 3,840,000
#define TSTRIDE 301        // lap tile row stride (floats), odd -> conflict-free
#define LT 12              // per-row top-LT candidate list for best-free-column
#define SMEMF 16176        // floats: tile + rowmin + lists + matched bitmap (64.7 KB)

// float offsets into smem
#define OFF_RMV 15072      // 50 f32 row min
#define OFF_RMC 15136      // 50 i32 row argmin col
#define OFF_LV  15200      // 50*12 f32 list values (ascending)
#define OFF_LC  15800      // 50*12 u16 list columns (300 floats)
#define OFF_MB  16100      // 300-byte matched-column bitmap (76 ints)

// NOTE (R2): warm positive v infeasible for rectangular LAP dual. (R4): auction ARR
// net-negative (price increments too small vs popular-column concentration). Current
// design: greedy row-argmin init + matched-slot exact SAP (labels only on matched
// columns, free columns tracked via per-row best-free scalar; v==0 on free always).

// ---------------- DPP wave-min helper (wave64, all lanes active) ----------------
template<int CTRL, int RMASK>
__device__ __forceinline__ double dpp_minstep_f64(double x) {
    long long bb = __double_as_longlong(x);
    int lo = (int)(bb & 0xFFFFFFFFll);
    int hi = (int)(bb >> 32);
    int mlo = __builtin_amdgcn_update_dpp(lo, lo, CTRL, RMASK, 0xF, false);
    int mhi = __builtin_amdgcn_update_dpp(hi, hi, CTRL, RMASK, 0xF, false);
    double other = __longlong_as_double(((long long)mhi << 32) | (long long)(unsigned)mlo);
    return fmin(x, other);
}
__device__ __forceinline__ double wave_min_f64(double x) {
    x = dpp_minstep_f64<0xB1, 0xF>(x);
    x = dpp_minstep_f64<0x4E, 0xF>(x);
    x = dpp_minstep_f64<0x141, 0xF>(x);
    x = dpp_minstep_f64<0x140, 0xF>(x);
    x = dpp_minstep_f64<0x142, 0xA>(x);   // lanes 16-31,48-63 <- lane 15/47
    x = dpp_minstep_f64<0x143, 0xC>(x);   // lanes 32-63 <- lane 31; lane 63 = global min
    long long bb = __double_as_longlong(x);
    int lo = __builtin_amdgcn_readlane((int)(bb & 0xFFFFFFFFll), 63);
    int hi = __builtin_amdgcn_readlane((int)(bb >> 32), 63);
    return __longlong_as_double(((long long)hi << 32) | (long long)(unsigned)lo);
}
__device__ __forceinline__ double readlane_f64(double x, int lane) {
    long long bb = __double_as_longlong(x);
    int lo = __builtin_amdgcn_readlane((int)(bb & 0xFFFFFFFFll), lane);
    int hi = __builtin_amdgcn_readlane((int)(bb >> 32), lane);
    return __longlong_as_double(((long long)hi << 32) | (long long)(unsigned)lo);
}
__device__ __forceinline__ float readlane_f32(float x, int lane) {
    return __int_as_float(__builtin_amdgcn_readlane(__float_as_int(x), lane));
}
__device__ __forceinline__ double shfl_f64(double x, int lane) {
    long long bb = __double_as_longlong(x);
    int lo = __shfl((int)(bb & 0xFFFFFFFFll), lane);
    int hi = __shfl((int)(bb >> 32), lane);
    return __longlong_as_double(((long long)hi << 32) | (long long)(unsigned)lo);
}
__device__ __forceinline__ void wave_argmin_f32(float &bv, int &bj) {
    #pragma unroll
    for (int off = 32; off > 0; off >>= 1) {
        float ov = __shfl_xor(bv, off);
        int   oj = __shfl_xor(bj, off);
        if (ov < bv || (ov == bv && oj < bj)) { bv = ov; bj = oj; }
    }
}

// Identical formula/op-order used by BOTH paths -> bitwise-identical cost values.
__device__ __forceinline__ float giou_cost(
    float plt0, float plt1, float plt2, float prb0, float prb1, float prb2, float pvol,
    float tlt0, float tlt1, float tlt2, float trb0, float trb1, float trb2, float tvol)
{
    float inter = fmaxf(fminf(prb0,trb0) - fmaxf(plt0,tlt0), 0.f);
    inter *= fmaxf(fminf(prb1,trb1) - fmaxf(plt1,tlt1), 0.f);
    inter *= fmaxf(fminf(prb2,trb2) - fmaxf(plt2,tlt2), 0.f);
    float evol = fmaxf(fmaxf(prb0,trb0) - fminf(plt0,tlt0), 0.f);
    evol *= fmaxf(fmaxf(prb1,trb1) - fminf(plt1,tlt1), 0.f);
    evol *= fmaxf(fmaxf(prb2,trb2) - fminf(plt2,tlt2), 0.f);
    float uni = pvol + tvol - inter;
    return inter/uni - (evol - uni)/evol;
}

__global__ __launch_bounds__(1024) void fused_kernel(
    const float* __restrict__ pred_kp, const float* __restrict__ pred_boxes,
    const float* __restrict__ tgt_boxes, const float* __restrict__ tgt_kp,
    float* __restrict__ C, float* __restrict__ out_idx)
{
    __shared__ __align__(16) float smem[SMEMF];
    const int bid = blockIdx.x;
    const int tid = threadIdx.x;

    if (bid >= BSZ) {
        // ================= cost-matrix path: 64 preds x 80 tgts per block =================
        const int cb = bid - BSZ;
        const int pb = cb % 75, tb = cb / 75;
        const int p0 = pb * 64, t0 = tb * 80;
        float* s_dk   = smem;            // 80 x 56 (padded, 16B-aligned rows)
        float* s_tbox = smem + 4480;     // 80 x 12: lt0-2, rb0-2, vol, pad, pad, s0-2
        float* s_pk   = smem + 5440;     // 64 x 51

        if (tid < 80) {
            const float* tb6 = tgt_boxes + (size_t)(t0 + tid) * 6;
            float c0=tb6[0], c1=tb6[1], c2=tb6[2], s0=tb6[3], s1=tb6[4], s2=tb6[5];
            float l0=c0-0.5f*s0, l1=c1-0.5f*s1, l2=c2-0.5f*s2;
            float r0=c0+0.5f*s0, r1=c1+0.5f*s1, r2=c2+0.5f*s2;
            float* tw = s_tbox + tid*12;
            tw[0]=l0; tw[1]=l1; tw[2]=l2; tw[3]=r0; tw[4]=r1; tw[5]=r2;
            tw[6]=(r0-l0)*(r1-l1)*(r2-l2);
            tw[9]=s0; tw[10]=s1; tw[11]=s2;
        }
        __syncthreads();
        for (int e = tid; e < 80*K3; e += 1024) {
            int t = e / K3; int c = e - t*K3; int d = c % 3;
            float kp = tgt_kp[(size_t)t0*K3 + e];
            s_dk[t*56 + c] = (kp - s_tbox[t*12 + d]) / s_tbox[t*12 + 9 + d];
        }
        for (int e = tid; e < 64*K3; e += 1024)
            s_pk[e] = pred_kp[(size_t)p0*K3 + e];
        __syncthreads();

        const int pl = tid & 63, g = tid >> 6;
        float a[K3];
        #pragma unroll
        for (int c = 0; c < K3; ++c) a[c] = s_pk[pl*K3 + c];
        const int p = p0 + pl;
        const float* pb6 = pred_boxes + (size_t)p * 6;
        float pc0=pb6[0],pc1=pb6[1],pc2=pb6[2],ps0=pb6[3],ps1=pb6[4],ps2=pb6[5];
        float plt0=pc0-0.5f*ps0, plt1=pc1-0.5f*ps1, plt2=pc2-0.5f*ps2;
        float prb0=pc0+0.5f*ps0, prb1=pc1+0.5f*ps1, prb2=pc2+0.5f*ps2;
        float pvol=(prb0-plt0)*(prb1-plt1)*(prb2-plt2);

        #pragma unroll
        for (int k = 0; k < 5; ++k) {
            int tl = g*5 + k;                       // wave-uniform -> broadcast LDS reads
            const float* bbp = s_dk + tl*56;
            float sum = 0.f;
            #pragma unroll
            for (int c4 = 0; c4 < 12; ++c4) {       // ascending c, serial adds (order fixed)
                float4 q = *(const float4*)(bbp + 4*c4);
                sum += fabsf(a[4*c4+0] - q.x);
                sum += fabsf(a[4*c4+1] - q.y);
                sum += fabsf(a[4*c4+2] - q.z);
                sum += fabsf(a[4*c4+3] - q.w);
            }
            sum += fabsf(a[48] - bbp[48]);
            sum += fabsf(a[49] - bbp[49]);
            sum += fabsf(a[50] - bbp[50]);
            const float* tw = s_tbox + tl*12;
            float g_ = giou_cost(plt0,plt1,plt2,prb0,prb1,prb2,pvol,
                                 tw[0],tw[1],tw[2],tw[3],tw[4],tw[5],tw[6]);
            C[(size_t)p*NTGT + (t0+tl)] = sum - g_;
        }
        return;
    }

    // ================= LAP path: one block per batch =================
    const int b = bid;
    const int ln = tid & 63, w = tid >> 6;
    const int bq0 = b*NQ, bt0 = b*NT;
    float* tile = smem;                 // becomes [50][301] cost tile

    // stage tgt_kp slice into (future) tile area
    for (int e = tid; e < NT*K3; e += 1024)
        tile[e] = tgt_kp[(size_t)bt0*K3 + e];
    __syncthreads();

    // per-lane target row -> registers (every wave redundantly; lanes 0..49)
    float dk[K3];
    float tl0=0,tl1=0,tl2=0,tr0=0,tr1=0,tr2=0,tvol=0;
    if (ln < NT) {
        const float* tb6 = tgt_boxes + (size_t)(bt0+ln)*6;
        float c0=tb6[0],c1=tb6[1],c2=tb6[2],s0=tb6[3],s1=tb6[4],s2=tb6[5];
        tl0=c0-0.5f*s0; tl1=c1-0.5f*s1; tl2=c2-0.5f*s2;
        tr0=c0+0.5f*s0; tr1=c1+0.5f*s1; tr2=c2+0.5f*s2;
        tvol=(tr0-tl0)*(tr1-tl1)*(tr2-tl2);
        #pragma unroll
        for (int c = 0; c < K3; ++c) {
            int d = c % 3;
            float L = (d==0)?tl0:((d==1)?tl1:tl2);
            float S = (d==0)?s0:((d==1)?s1:s2);
            dk[c] = (tile[ln*K3 + c] - L) / S;
        }
    }
    __syncthreads();

    // build cost tile: wave w handles preds p = w, w+16, ... (bitwise same math as C path)
    for (int p = w; p < NQ; p += 16) {
        const float* prow = pred_kp + (size_t)(bq0+p)*K3;
        const float* pb6  = pred_boxes + (size_t)(bq0+p)*6;
        float pc0=pb6[0],pc1=pb6[1],pc2=pb6[2],ps0=pb6[3],ps1=pb6[4],ps2=pb6[5];
        float plt0=pc0-0.5f*ps0, plt1=pc1-0.5f*ps1, plt2=pc2-0.5f*ps2;
        float prb0=pc0+0.5f*ps0, prb1=pc1+0.5f*ps1, prb2=pc2+0.5f*ps2;
        float pvol=(prb0-plt0)*(prb1-plt1)*(prb2-plt2);
        if (ln < NT) {
            float sum = 0.f;
            #pragma unroll
            for (int c = 0; c < K3; ++c) sum += fabsf(prow[c] - dk[c]);
            float g_ = giou_cost(plt0,plt1,plt2,prb0,prb1,prb2,pvol,
                                 tl0,tl1,tl2,tr0,tr1,tr2,tvol);
            tile[ln*TSTRIDE + p] = sum - g_;
        }
    }
    __syncthreads();

    float* s_rmv = smem + OFF_RMV;
    int*   s_rmc = (int*)(smem + OFF_RMC);
    float* s_lv  = smem + OFF_LV;
    unsigned short* s_lc = (unsigned short*)(smem + OFF_LC);
    unsigned char*  s_mb = (unsigned char*)(smem + OFF_MB);

    // ---- per-row argmin scan for greedy init (all 16 waves in parallel) ----
    for (int r = w; r < NT; r += 16) {
        float bv = __builtin_inff(); int bj = 0x7fffffff;
        #pragma unroll
        for (int s = 0; s < 5; ++s) {
            int j = ln + 64*s;
            if (j < NQ) {
                float cv = tile[r*TSTRIDE + j];
                if (cv < bv || (cv == bv && j < bj)) { bv = cv; bj = j; }
            }
        }
        wave_argmin_f32(bv, bj);
        if (ln == 0) { s_rmv[r] = bv; s_rmc[r] = bj; }
    }
    // ---- per-row top-LT candidate list (ascending), all 16 waves in parallel ----
    for (int r = w; r < NT; r += 16) {
        float v5[5]; int excl = 0;
        #pragma unroll
        for (int s = 0; s < 5; ++s) {
            int j = ln + 64*s;
            v5[s] = (j < NQ) ? tile[r*TSTRIDE + j] : __builtin_inff();
        }
        for (int k = 0; k < LT; ++k) {
            float bv = __builtin_inff(); int bj = 0x7fffffff;
            #pragma unroll
            for (int s = 0; s < 5; ++s) {
                int j = ln + 64*s;
                bool ok = (j < NQ) && !((excl >> s) & 1);
                if (ok && (v5[s] < bv || (v5[s] == bv && j < bj))) { bv = v5[s]; bj = j; }
            }
            wave_argmin_f32(bv, bj);
            if (ln == 0) { s_lv[r*LT + k] = bv; s_lc[r*LT + k] = (unsigned short)bj; }
            if (ln == (bj & 63)) excl |= 1 << (bj >> 6);
        }
    }
    // zero matched bitmap (300 bytes as 76 ints, [16100,16176))
    for (int e = tid; e < 76; e += 1024) ((int*)(smem + OFF_MB))[e] = 0;
    __syncthreads();
    if (w != 0) return;                 // wave 0 continues alone; no more s_barrier

    // ---- greedy init: u[i] = rowmin, v = 0; claim argmin col first-row-wins ----
    double u = 0.0;
    int c4r = -1;                        // col4row[ln]
    if (ln < NT) u = (double)s_rmv[ln];
    int wantj = (ln < NT) ? s_rmc[ln] : -1;
    for (int r = 0; r < NT; ++r) {
        int j = __builtin_amdgcn_readlane(wantj, r);
        unsigned long long taken = __ballot((ln < NT) && (c4r == j));
        if (taken == 0ull && ln == r) c4r = j;
    }
    if (ln < NT && c4r >= 0) s_mb[c4r] = 1;
    __threadfence_block();

    // ---- best-free-column (bu) per row: list pointer + lazy validation ----
    float buval = __builtin_inff(); int bucol = 0x7fffffff; int buptr = LT;
    if (ln < NT) {
        buptr = 0;
        while (buptr < LT && s_mb[s_lc[ln*LT + buptr]]) ++buptr;
        if (buptr < LT) { buval = s_lv[ln*LT + buptr]; bucol = s_lc[ln*LT + buptr]; }
    }
    {
        unsigned long long rs = __ballot((ln < NT) && (buptr >= LT));
        while (rs) {                     // rare: full-row rescan over free cols
            int r = __builtin_ctzll(rs); rs &= rs - 1;
            float bv = __builtin_inff(); int bj = 0x7fffffff;
            #pragma unroll
            for (int s = 0; s < 5; ++s) {
                int j = ln + 64*s;
                if (j < NQ && !s_mb[j]) {
                    float cv = tile[r*TSTRIDE + j];
                    if (cv < bv || (cv == bv && j < bj)) { bv = cv; bj = j; }
                }
            }
            wave_argmin_f32(bv, bj);
            if (ln == r) { buval = bv; bucol = bj; }
        }
    }

    // ---- build matched-column slots: slot-lane ln<nm owns (mcol, mrow, vs) ----
    int nm = 0;
    int mcol = 0, mrow = 0, s4r = 0;
    double vs = 0.0;                     // column dual for this slot (v<=0 invariant)
    for (int r = 0; r < NT; ++r) {
        int cr = __builtin_amdgcn_readlane(c4r, r);
        if (cr >= 0) {
            if (ln == nm) { mcol = cr; mrow = r; }
            if (ln == r) s4r = nm;
            ++nm;
        }
    }

    const double DINF = __builtin_inf();

    // ---- matched-slot exact SAP (f64, reference op order) ----
    for (int curRow = 0; curRow < NT; ++curRow) {
        if (__builtin_amdgcn_readlane(c4r, curRow) >= 0) continue;
        bool open = (ln < nm);
        double sh = DINF; int pthr = -1;
        unsigned long long SRmask = 0ull;
        int i = curRow;
        double minVal = 0.0;
        double sinkCand = DINF; int sinkCol = -1, sinkRow = -1;

        for (int guard = 0; guard < 512; ++guard) {
            SRmask |= (1ull << i);
            float cf = tile[i*TSTRIDE + mcol];          // one load per lane (slot col)
            double u_i  = readlane_f64(u, i);
            float  bu_i = readlane_f32(buval, i);
            int    buc_i = __builtin_amdgcn_readlane(bucol, i);
            // best free col via row i: shortest = ((minVal + c) - u) - 0  (v=0 on free)
            double rbu = (minVal + (double)bu_i) - u_i;
            if (rbu < sinkCand) { sinkCand = rbu; sinkCol = buc_i; sinkRow = i; }
            // matched-slot label update (reference op order)
            double rr = ((minVal + (double)cf) - u_i) - vs;
            bool upd = open && (rr < sh);
            sh   = upd ? rr : sh;
            pthr = upd ? i : pthr;
            double m = wave_min_f64(open ? sh : DINF);
            if (sinkCand < m) { minVal = sinkCand; break; }   // sink = free column
            minVal = m;
            unsigned long long bb = __ballot(open && (sh == m));
            int slot = __builtin_ctzll(bb);
            if (ln == slot) open = false;
            i = __builtin_amdgcn_readlane(mrow, slot);
        }

        // ---- dual updates (pre-augment matching) ----
        bool valid = (ln < nm);
        double gg = shfl_f64(sh, (c4r >= 0) ? s4r : 0);   // sh at row's own slot
        bool inSR = (ln < NT) && ((SRmask >> ln) & 1ull);
        double du = (ln == curRow) ? minVal : (minVal - gg);
        u = inSR ? (u + du) : u;
        bool closedSlot = valid && !open;
        vs = closedSlot ? (vs - (minVal - sh)) : vs;

        // ---- augment along path; sink becomes new slot nm ----
        int jcol = sinkCol, jslot = nm, ii = sinkRow;
        if (ln == nm) { mcol = sinkCol; vs = 0.0; }
        for (int guard = 0; guard < 64; ++guard) {
            int oldc = __builtin_amdgcn_readlane(c4r, ii);
            int olds = __builtin_amdgcn_readlane(s4r, ii);
            if (ln == jslot) mrow = ii;
            if (ln == ii) { c4r = jcol; s4r = jslot; }
            if (ii == curRow) break;
            jcol = oldc; jslot = olds;
            ii = __builtin_amdgcn_readlane(pthr, jslot);
        }
        ++nm;
        if (ln == 0) s_mb[sinkCol] = 1;
        __threadfence_block();

        // ---- bu maintenance: only rows whose best-free col just got matched ----
        bool need = (ln < NT) && (bucol == sinkCol);
        if (need) {
            while (buptr < LT && s_mb[s_lc[ln*LT + buptr]]) ++buptr;
            if (buptr < LT) { buval = s_lv[ln*LT + buptr]; bucol = s_lc[ln*LT + buptr]; need = false; }
        }
        unsigned long long rs = __ballot(need);
        while (rs) {
            int r = __builtin_ctzll(rs); rs &= rs - 1;
            float bv = __builtin_inff(); int bj = 0x7fffffff;
            #pragma unroll
            for (int s = 0; s < 5; ++s) {
                int j = ln + 64*s;
                if (j < NQ && !s_mb[j]) {
                    float cv = tile[r*TSTRIDE + j];
                    if (cv < bv || (cv == bv && j < bj)) { bv = cv; bj = j; }
                }
            }
            wave_argmin_f32(bv, bj);
            if (ln == r) { buval = bv; bucol = bj; }
        }
    }

    // ---- emit indices (argsort of matched pred indices) ----
    int* smem_i = (int*)smem;                       // tile is dead
    __threadfence_block();
    if (ln < NT) smem_i[ln] = c4r;
    __threadfence_block();
    int myc = c4r;
    int rank = 0;
    for (int s2 = 0; s2 < NT; ++s2) rank += (smem_i[s2] < myc) ? 1 : 0;
    if (ln < NT) {
        out_idx[b*(2*NT) + rank]      = (float)myc; // sorted pred (q) indices
        out_idx[b*(2*NT) + NT + rank] = (float)ln;  // matched tgt (t) indices
    }
}

extern "C" void kernel_launch(void* const* d_in, const int* in_sizes, int n_in,
                              void* d_out, int out_size, void* d_ws, size_t ws_size,
                              hipStream_t stream)
{
    const float* pred_kp    = (const float*)d_in[0];
    const float* pred_boxes = (const float*)d_in[1];
    const float* tgt_boxes  = (const float*)d_in[2];
    const float* tgt_kp     = (const float*)d_in[3];
    float* C   = (float*)d_out;
    float* idx = C + NC;
    // blocks 0..15: per-batch LAP (dispatched first); blocks 16..765: cost matrix
    fused_kernel<<<dim3(BSZ + 750), 1024, 0, stream>>>(
        pred_kp, pred_boxes, tgt_boxes, tgt_kp, C, idx);
}

// Round 6
// 130.568 us; speedup vs baseline: 1.2884x; 1.2884x over previous
//
#include <hip/hip_runtime.h>
#include <math.h>

#define BSZ 16
#define NQ 300
#define NT 50
#define K3 51
#define NPRED (BSZ*NQ)     // 4800
#define NTGT  (BSZ*NT)     // 800
#define NC    (NPRED*NTGT) // 3,840,000
#define TSTRIDE 301        // lap tile row stride (floats), odd -> conflict-free
#define SMEMF 15232        // floats: 50*301 tile + rowmin scratch (60.9 KB, 2 blk/CU)

// DEAD ENDS (do not retry):
//  R2: warm positive v (column reduction) -> infeasible for rectangular LAP dual.
//  R4: serial auction ARR -> net-negative (tiny price increments vs popular-column
//      concentration of this additive cost structure).
//  R5: matched-slot SAP + top-LT free lists -> bu-rescan storms (lists concentrate
//      on popular columns, exhausted immediately) 74->113us.
// Current: R3 structure + exact u32-key fast argmin (bit-identical, fallback exact).

// ---------------- DPP wave-min helpers (wave64, all lanes active) ----------------
template<int CTRL, int RMASK>
__device__ __forceinline__ double dpp_minstep_f64(double x) {
    long long bb = __double_as_longlong(x);
    int lo = (int)(bb & 0xFFFFFFFFll);
    int hi = (int)(bb >> 32);
    int mlo = __builtin_amdgcn_update_dpp(lo, lo, CTRL, RMASK, 0xF, false);
    int mhi = __builtin_amdgcn_update_dpp(hi, hi, CTRL, RMASK, 0xF, false);
    double other = __longlong_as_double(((long long)mhi << 32) | (long long)(unsigned)mlo);
    return fmin(x, other);
}
__device__ __forceinline__ double wave_min_f64(double x) {
    x = dpp_minstep_f64<0xB1, 0xF>(x);
    x = dpp_minstep_f64<0x4E, 0xF>(x);
    x = dpp_minstep_f64<0x141, 0xF>(x);
    x = dpp_minstep_f64<0x140, 0xF>(x);
    x = dpp_minstep_f64<0x142, 0xA>(x);   // lanes 16-31,48-63 <- lane 15/47
    x = dpp_minstep_f64<0x143, 0xC>(x);   // lanes 32-63 <- lane 31; lane 63 = global min
    long long bb = __double_as_longlong(x);
    int lo = __builtin_amdgcn_readlane((int)(bb & 0xFFFFFFFFll), 63);
    int hi = __builtin_amdgcn_readlane((int)(bb >> 32), 63);
    return __longlong_as_double(((long long)hi << 32) | (long long)(unsigned)lo);
}
template<int CTRL, int RMASK>
__device__ __forceinline__ unsigned int dpp_minstep_u32(unsigned int x) {
    unsigned int o = (unsigned int)__builtin_amdgcn_update_dpp((int)x, (int)x, CTRL, RMASK, 0xF, false);
    return (x < o) ? x : o;
}
__device__ __forceinline__ unsigned int wave_min_u32(unsigned int x) {
    x = dpp_minstep_u32<0xB1, 0xF>(x);
    x = dpp_minstep_u32<0x4E, 0xF>(x);
    x = dpp_minstep_u32<0x141, 0xF>(x);
    x = dpp_minstep_u32<0x140, 0xF>(x);
    x = dpp_minstep_u32<0x142, 0xA>(x);
    x = dpp_minstep_u32<0x143, 0xC>(x);
    return (unsigned int)__builtin_amdgcn_readlane((int)x, 63);
}
__device__ __forceinline__ double readlane_f64(double x, int lane) {
    long long bb = __double_as_longlong(x);
    int lo = __builtin_amdgcn_readlane((int)(bb & 0xFFFFFFFFll), lane);
    int hi = __builtin_amdgcn_readlane((int)(bb >> 32), lane);
    return __longlong_as_double(((long long)hi << 32) | (long long)(unsigned)lo);
}

// Identical formula/op-order used by BOTH paths -> bitwise-identical cost values.
__device__ __forceinline__ float giou_cost(
    float plt0, float plt1, float plt2, float prb0, float prb1, float prb2, float pvol,
    float tlt0, float tlt1, float tlt2, float trb0, float trb1, float trb2, float tvol)
{
    float inter = fmaxf(fminf(prb0,trb0) - fmaxf(plt0,tlt0), 0.f);
    inter *= fmaxf(fminf(prb1,trb1) - fmaxf(plt1,tlt1), 0.f);
    inter *= fmaxf(fminf(prb2,trb2) - fmaxf(plt2,tlt2), 0.f);
    float evol = fmaxf(fmaxf(prb0,trb0) - fminf(plt0,tlt0), 0.f);
    evol *= fmaxf(fmaxf(prb1,trb1) - fminf(plt1,tlt1), 0.f);
    evol *= fmaxf(fmaxf(prb2,trb2) - fminf(plt2,tlt2), 0.f);
    float uni = pvol + tvol - inter;
    return inter/uni - (evol - uni)/evol;
}

__global__ __launch_bounds__(1024) void fused_kernel(
    const float* __restrict__ pred_kp, const float* __restrict__ pred_boxes,
    const float* __restrict__ tgt_boxes, const float* __restrict__ tgt_kp,
    float* __restrict__ C, float* __restrict__ out_idx)
{
    __shared__ __align__(16) float smem[SMEMF];
    const int bid = blockIdx.x;
    const int tid = threadIdx.x;

    if (bid >= BSZ) {
        // ================= cost-matrix path: 64 preds x 80 tgts per block =================
        const int cb = bid - BSZ;
        const int pb = cb % 75, tb = cb / 75;
        const int p0 = pb * 64, t0 = tb * 80;
        float* s_dk   = smem;            // 80 x 56 (padded, 16B-aligned rows)
        float* s_tbox = smem + 4480;     // 80 x 12: lt0-2, rb0-2, vol, pad, pad, s0-2
        float* s_pk   = smem + 5440;     // 64 x 51

        if (tid < 80) {
            const float* tb6 = tgt_boxes + (size_t)(t0 + tid) * 6;
            float c0=tb6[0], c1=tb6[1], c2=tb6[2], s0=tb6[3], s1=tb6[4], s2=tb6[5];
            float l0=c0-0.5f*s0, l1=c1-0.5f*s1, l2=c2-0.5f*s2;
            float r0=c0+0.5f*s0, r1=c1+0.5f*s1, r2=c2+0.5f*s2;
            float* tw = s_tbox + tid*12;
            tw[0]=l0; tw[1]=l1; tw[2]=l2; tw[3]=r0; tw[4]=r1; tw[5]=r2;
            tw[6]=(r0-l0)*(r1-l1)*(r2-l2);
            tw[9]=s0; tw[10]=s1; tw[11]=s2;
        }
        __syncthreads();
        for (int e = tid; e < 80*K3; e += 1024) {
            int t = e / K3; int c = e - t*K3; int d = c % 3;
            float kp = tgt_kp[(size_t)t0*K3 + e];
            s_dk[t*56 + c] = (kp - s_tbox[t*12 + d]) / s_tbox[t*12 + 9 + d];
        }
        for (int e = tid; e < 64*K3; e += 1024)
            s_pk[e] = pred_kp[(size_t)p0*K3 + e];
        __syncthreads();

        const int pl = tid & 63, g = tid >> 6;
        float a[K3];
        #pragma unroll
        for (int c = 0; c < K3; ++c) a[c] = s_pk[pl*K3 + c];
        const int p = p0 + pl;
        const float* pb6 = pred_boxes + (size_t)p * 6;
        float pc0=pb6[0],pc1=pb6[1],pc2=pb6[2],ps0=pb6[3],ps1=pb6[4],ps2=pb6[5];
        float plt0=pc0-0.5f*ps0, plt1=pc1-0.5f*ps1, plt2=pc2-0.5f*ps2;
        float prb0=pc0+0.5f*ps0, prb1=pc1+0.5f*ps1, prb2=pc2+0.5f*ps2;
        float pvol=(prb0-plt0)*(prb1-plt1)*(prb2-plt2);

        #pragma unroll
        for (int k = 0; k < 5; ++k) {
            int tl = g*5 + k;                       // wave-uniform -> broadcast LDS reads
            const float* bbp = s_dk + tl*56;
            float sum = 0.f;
            #pragma unroll
            for (int c4 = 0; c4 < 12; ++c4) {       // ascending c, serial adds (order fixed)
                float4 q = *(const float4*)(bbp + 4*c4);
                sum += fabsf(a[4*c4+0] - q.x);
                sum += fabsf(a[4*c4+1] - q.y);
                sum += fabsf(a[4*c4+2] - q.z);
                sum += fabsf(a[4*c4+3] - q.w);
            }
            sum += fabsf(a[48] - bbp[48]);
            sum += fabsf(a[49] - bbp[49]);
            sum += fabsf(a[50] - bbp[50]);
            const float* tw = s_tbox + tl*12;
            float g_ = giou_cost(plt0,plt1,plt2,prb0,prb1,prb2,pvol,
                                 tw[0],tw[1],tw[2],tw[3],tw[4],tw[5],tw[6]);
            C[(size_t)p*NTGT + (t0+tl)] = sum - g_;
        }
        return;
    }

    // ================= LAP path: one block per batch =================
    const int b = bid;
    const int ln = tid & 63, w = tid >> 6;
    const int bq0 = b*NQ, bt0 = b*NT;
    float* tile = smem;                 // becomes [50][301] cost tile

    // stage tgt_kp slice into (future) tile area
    for (int e = tid; e < NT*K3; e += 1024)
        tile[e] = tgt_kp[(size_t)bt0*K3 + e];
    __syncthreads();

    // per-lane target row -> registers (every wave redundantly; lanes 0..49)
    float dk[K3];
    float tl0=0,tl1=0,tl2=0,tr0=0,tr1=0,tr2=0,tvol=0;
    if (ln < NT) {
        const float* tb6 = tgt_boxes + (size_t)(bt0+ln)*6;
        float c0=tb6[0],c1=tb6[1],c2=tb6[2],s0=tb6[3],s1=tb6[4],s2=tb6[5];
        tl0=c0-0.5f*s0; tl1=c1-0.5f*s1; tl2=c2-0.5f*s2;
        tr0=c0+0.5f*s0; tr1=c1+0.5f*s1; tr2=c2+0.5f*s2;
        tvol=(tr0-tl0)*(tr1-tl1)*(tr2-tl2);
        #pragma unroll
        for (int c = 0; c < K3; ++c) {
            int d = c % 3;
            float L = (d==0)?tl0:((d==1)?tl1:tl2);
            float S = (d==0)?s0:((d==1)?s1:s2);
            dk[c] = (tile[ln*K3 + c] - L) / S;
        }
    }
    __syncthreads();

    // build cost tile: wave w handles preds p = w, w+16, ... (bitwise same math as C path)
    for (int p = w; p < NQ; p += 16) {
        const float* prow = pred_kp + (size_t)(bq0+p)*K3;
        const float* pb6  = pred_boxes + (size_t)(bq0+p)*6;
        float pc0=pb6[0],pc1=pb6[1],pc2=pb6[2],ps0=pb6[3],ps1=pb6[4],ps2=pb6[5];
        float plt0=pc0-0.5f*ps0, plt1=pc1-0.5f*ps1, plt2=pc2-0.5f*ps2;
        float prb0=pc0+0.5f*ps0, prb1=pc1+0.5f*ps1, prb2=pc2+0.5f*ps2;
        float pvol=(prb0-plt0)*(prb1-plt1)*(prb2-plt2);
        if (ln < NT) {
            float sum = 0.f;
            #pragma unroll
            for (int c = 0; c < K3; ++c) sum += fabsf(prow[c] - dk[c]);
            float g_ = giou_cost(plt0,plt1,plt2,prb0,prb1,prb2,pvol,
                                 tl0,tl1,tl2,tr0,tr1,tr2,tvol);
            tile[ln*TSTRIDE + p] = sum - g_;
        }
    }
    __syncthreads();

    // ---- per-row argmin scan for greedy JV init (all 16 waves in parallel) ----
    // Placed beyond the Dijkstra's max speculative read index (49*301+319 = 15068).
    float* s_rmv = smem + 15072;          // 50 floats: row min value
    int*   s_rmc = (int*)(smem + 15136);  // 50 ints:   row argmin column
    for (int r = w; r < NT; r += 16) {
        float bv = __builtin_inff(); int bj = 0x7fffffff;
        #pragma unroll
        for (int s = 0; s < 5; ++s) {
            int j = ln + 64*s;
            if (j < NQ) {
                float cv = tile[r*TSTRIDE + j];
                if (cv < bv || (cv == bv && j < bj)) { bv = cv; bj = j; }
            }
        }
        #pragma unroll
        for (int off = 32; off > 0; off >>= 1) {
            float ov = __shfl_xor(bv, off);
            int   oj = __shfl_xor(bj, off);
            if (ov < bv || (ov == bv && oj < bj)) { bv = ov; bj = oj; }
        }
        if (ln == 0) { s_rmv[r] = bv; s_rmc[r] = bj; }
    }
    __syncthreads();
    if (w != 0) return;                 // wave 0 continues alone; no more s_barrier

    // ---- register-resident JV shortest-augmenting-path (float64 duals) ----
    // Greedy init: u[i] = min_j c[i][j], v = 0 (feasible dual, tight at row argmin);
    // assign each row its argmin column first-row-wins. Only contested rows need
    // Dijkstra, and they start from already-tight duals.
    // lane ln owns columns j = ln + 64*s (s=0..4); slot 4 invalid for ln>=44
    double u = 0.0;                     // dual for row ln (ln<50)
    int c4r = -1;                       // col4row[ln]
    if (ln < NT) u = (double)s_rmv[ln];
    int wantj = (ln < NT) ? s_rmc[ln] : -1;
    for (int r = 0; r < NT; ++r) {
        int j = __builtin_amdgcn_readlane(wantj, r);
        unsigned long long taken = __ballot((ln < NT) && (c4r == j));
        if (taken == 0ull && ln == r) c4r = j;
    }

    double v[5], sh[5];
    int pth[5];
    #pragma unroll
    for (int s = 0; s < 5; ++s) v[s] = 0.0;
    const double DINF = __builtin_inf();

    for (int curRow = 0; curRow < NT; ++curRow) {
        if (__builtin_amdgcn_readlane(c4r, curRow) >= 0) continue;  // greedy-assigned
        #pragma unroll
        for (int s = 0; s < 5; ++s) { sh[s] = DINF; pth[s] = -1; }
        int SCm = (ln < 44) ? 0 : 0x10;            // invalid slot pre-closed
        unsigned long long SRmask = 0ull;
        int i = curRow;
        double minVal = 0.0;
        int sink = -1;

        while (true) {
            SRmask |= (1ull << i);
            float cf[5];
            #pragma unroll
            for (int s = 0; s < 5; ++s) cf[s] = tile[i*TSTRIDE + ln + 64*s];
            double u_i = readlane_f64(u, i);       // i is wave-uniform -> v_readlane
            double e[5];
            #pragma unroll
            for (int s = 0; s < 5; ++s) {
                bool open = ((SCm >> s) & 1) == 0;
                double r = ((minVal + (double)cf[s]) - u_i) - v[s];  // reference op order
                bool upd = open && (r < sh[s]);
                sh[s]  = upd ? r : sh[s];
                pth[s] = upd ? i : pth[s];
                e[s] = open ? sh[s] : DINF;
            }
            // depth-3 fmin tree (exact: fmin assoc/comm over NaN-free values incl inf)
            double lmin = fmin(fmin(fmin(e[0], e[1]), fmin(e[2], e[3])), e[4]);
            // per-lane argslot, smallest s on exact ties (= smallest j within lane)
            int aslot = (e[0]==lmin) ? 0 : (e[1]==lmin) ? 1 :
                        (e[2]==lmin) ? 2 : (e[3]==lmin) ? 3 : 4;
            // ---- fast exact argmin: sortable-u32 key = folded hi32 of f64 bits ----
            // Monotonic (non-strict) in lmin. If exactly ONE lane attains the min
            // key, that lane provably holds the unique exact f64 min (any exact tie
            // would share the key) -> skip f64 DPP + 5 ballots. Collision -> exact
            // fallback (verbatim R3 path). Result bit-identical either way.
            unsigned int khi = (unsigned int)((unsigned long long)__double_as_longlong(lmin) >> 32);
            unsigned int ukey = khi ^ (((int)khi < 0) ? 0xFFFFFFFFu : 0x80000000u);
            unsigned int kmin = wave_min_u32(ukey);
            unsigned long long cands = __ballot(ukey == kmin);
            double m; int jstar;
            if (__popcll(cands) == 1) {
                int lstar = __builtin_ctzll(cands);
                m = readlane_f64(lmin, lstar);
                int as_ = __builtin_amdgcn_readlane(aslot, lstar);
                jstar = as_*64 + lstar;
            } else {
                m = wave_min_f64(lmin);
                unsigned long long b0 = __ballot((((SCm >> 0) & 1) == 0) && (sh[0] == m));
                unsigned long long b1 = __ballot((((SCm >> 1) & 1) == 0) && (sh[1] == m));
                unsigned long long b2 = __ballot((((SCm >> 2) & 1) == 0) && (sh[2] == m));
                unsigned long long b3 = __ballot((((SCm >> 3) & 1) == 0) && (sh[3] == m));
                unsigned long long b4 = __ballot((((SCm >> 4) & 1) == 0) && (sh[4] == m));
                if      (b0) jstar =       __builtin_ctzll(b0);
                else if (b1) jstar =  64 + __builtin_ctzll(b1);
                else if (b2) jstar = 128 + __builtin_ctzll(b2);
                else if (b3) jstar = 192 + __builtin_ctzll(b3);
                else         jstar = 256 + __builtin_ctzll(b4);
            }
            minVal = m;
            // row4col[jstar] via col4row ballot (col4row constant during Dijkstra)
            unsigned long long mm = __ballot((ln < NT) && (c4r == jstar));
            // close column jstar
            if (ln == (jstar & 63)) SCm |= 1 << (jstar >> 6);
            if (mm == 0ull) { sink = jstar; break; }
            i = __builtin_ctzll(mm);
        }

        // ---- dual updates (pre-augment col4row) ----
        int cg  = (c4r >= 0) ? c4r : 0;
        int gow = cg & 63, gsl = cg >> 6;
        double g0 = __shfl(sh[0], gow);
        double g1 = __shfl(sh[1], gow);
        double g2 = __shfl(sh[2], gow);
        double g3 = __shfl(sh[3], gow);
        double g4 = __shfl(sh[4], gow);
        double gg = g0;
        gg = (gsl == 1) ? g1 : gg;
        gg = (gsl == 2) ? g2 : gg;
        gg = (gsl == 3) ? g3 : gg;
        gg = (gsl == 4) ? g4 : gg;
        bool inSR = (ln < NT) && ((SRmask >> ln) & 1ull);
        double du = (ln == curRow) ? minVal : (minVal - gg);
        u = inSR ? (u + du) : u;
        #pragma unroll
        for (int s = 0; s < 5; ++s) {
            bool closed = ((SCm >> s) & 1) != 0;
            v[s] = closed ? (v[s] - (minVal - sh[s])) : v[s];
        }

        // ---- augment (uniform j/i chain -> readlane) ----
        int j = sink;
        while (true) {
            int ow2 = j & 63, sl2 = j >> 6;
            int ps = pth[0];
            ps = (sl2==1) ? pth[1] : ps;
            ps = (sl2==2) ? pth[2] : ps;
            ps = (sl2==3) ? pth[3] : ps;
            ps = (sl2==4) ? pth[4] : ps;
            int ii = __builtin_amdgcn_readlane(ps, ow2);   // path[j]
            int jj = __builtin_amdgcn_readlane(c4r, ii);   // old col4row[ii]
            if (ln == ii) c4r = j;                          // col4row[ii] = j
            j = jj;
            if (ii == curRow) break;
        }
    }

    // ---- emit indices (argsort of matched pred indices) ----
    int* smem_i = (int*)smem;                       // tile is dead
    __threadfence_block();
    if (ln < NT) smem_i[ln] = c4r;
    __threadfence_block();
    int myc = c4r;
    int rank = 0;
    for (int s2 = 0; s2 < NT; ++s2) rank += (smem_i[s2] < myc) ? 1 : 0;
    if (ln < NT) {
        out_idx[b*(2*NT) + rank]      = (float)myc; // sorted pred (q) indices
        out_idx[b*(2*NT) + NT + rank] = (float)ln;  // matched tgt (t) indices
    }
}

extern "C" void kernel_launch(void* const* d_in, const int* in_sizes, int n_in,
                              void* d_out, int out_size, void* d_ws, size_t ws_size,
                              hipStream_t stream)
{
    const float* pred_kp    = (const float*)d_in[0];
    const float* pred_boxes = (const float*)d_in[1];
    const float* tgt_boxes  = (const float*)d_in[2];
    const float* tgt_kp     = (const float*)d_in[3];
    float* C   = (float*)d_out;
    float* idx = C + NC;
    // blocks 0..15: per-batch LAP (dispatched first); blocks 16..765: cost matrix
    fused_kernel<<<dim3(BSZ + 750), 1024, 0, stream>>>(
        pred_kp, pred_boxes, tgt_boxes, tgt_kp, C, idx);
}

// Round 7
// 127.944 us; speedup vs baseline: 1.3148x; 1.0205x over previous
//
#include <hip/hip_runtime.h>
#include <math.h>

#define BSZ 16
#define NQ 300
#define NT 50
#define K3 51
#define NPRED (BSZ*NQ)     // 4800
#define NTGT  (BSZ*NT)     // 800
#define NC    (NPRED*NTGT) // 3,840,000
#define TSTRIDE 301        // lap tile row stride (floats), odd -> conflict-free
#define SMEMF 15232        // floats: 50*301 tile + rowmin scratch (60.9 KB, 2 blk/CU)

// DEAD ENDS (do not retry):
//  R2: warm positive v (column reduction) -> infeasible for rectangular LAP dual.
//  R4: serial auction ARR -> net-negative (tiny price increments vs popular-column
//      concentration of this additive cost structure).
//  R5: matched-slot SAP + top-LT free lists -> bu-rescan storms 74->113us.
//  R3/R6 lesson: fmin-tree and key-argmin alone ~neutral -> chain is dominated by
//      LDS round-trip + f64 cross-lane ops, not the reduction tree.
// Current: R3 control structure, 5-contiguous-column packing (j=5*ln+s, lane-major
// tie order, 3 LDS issues, 1-ballot argmin) + f32 labels/duals (exact f32 SAP;
// near-tie deviations vs scipy tolerated by harness threshold, absmax<=6).

// ---------------- DPP wave-min helpers (wave64, all lanes active) ----------------
template<int CTRL, int RMASK>
__device__ __forceinline__ unsigned int dpp_minstep_u32(unsigned int x) {
    unsigned int o = (unsigned int)__builtin_amdgcn_update_dpp((int)x, (int)x, CTRL, RMASK, 0xF, false);
    return (x < o) ? x : o;
}
__device__ __forceinline__ unsigned int wave_min_u32(unsigned int x) {
    x = dpp_minstep_u32<0xB1, 0xF>(x);
    x = dpp_minstep_u32<0x4E, 0xF>(x);
    x = dpp_minstep_u32<0x141, 0xF>(x);
    x = dpp_minstep_u32<0x140, 0xF>(x);
    x = dpp_minstep_u32<0x142, 0xA>(x);   // lanes 16-31,48-63 <- lane 15/47
    x = dpp_minstep_u32<0x143, 0xC>(x);   // lanes 32-63 <- lane 31; lane 63 = min
    return (unsigned int)__builtin_amdgcn_readlane((int)x, 63);
}
__device__ __forceinline__ float readlane_f32(float x, int lane) {
    return __int_as_float(__builtin_amdgcn_readlane(__float_as_int(x), lane));
}
// strictly monotonic, bijective f32 -> u32 key (no -0 can occur in labels)
__device__ __forceinline__ unsigned int f32key(float x) {
    unsigned int b = (unsigned int)__float_as_int(x);
    return b ^ (((int)b < 0) ? 0xFFFFFFFFu : 0x80000000u);
}

// Identical formula/op-order used by BOTH paths -> bitwise-identical cost values.
__device__ __forceinline__ float giou_cost(
    float plt0, float plt1, float plt2, float prb0, float prb1, float prb2, float pvol,
    float tlt0, float tlt1, float tlt2, float trb0, float trb1, float trb2, float tvol)
{
    float inter = fmaxf(fminf(prb0,trb0) - fmaxf(plt0,tlt0), 0.f);
    inter *= fmaxf(fminf(prb1,trb1) - fmaxf(plt1,tlt1), 0.f);
    inter *= fmaxf(fminf(prb2,trb2) - fmaxf(plt2,tlt2), 0.f);
    float evol = fmaxf(fmaxf(prb0,trb0) - fminf(plt0,tlt0), 0.f);
    evol *= fmaxf(fmaxf(prb1,trb1) - fminf(plt1,tlt1), 0.f);
    evol *= fmaxf(fmaxf(prb2,trb2) - fminf(plt2,tlt2), 0.f);
    float uni = pvol + tvol - inter;
    return inter/uni - (evol - uni)/evol;
}

__global__ __launch_bounds__(1024) void fused_kernel(
    const float* __restrict__ pred_kp, const float* __restrict__ pred_boxes,
    const float* __restrict__ tgt_boxes, const float* __restrict__ tgt_kp,
    float* __restrict__ C, float* __restrict__ out_idx)
{
    __shared__ __align__(16) float smem[SMEMF];
    const int bid = blockIdx.x;
    const int tid = threadIdx.x;

    if (bid >= BSZ) {
        // ================= cost-matrix path: 64 preds x 80 tgts per block =================
        const int cb = bid - BSZ;
        const int pb = cb % 75, tb = cb / 75;
        const int p0 = pb * 64, t0 = tb * 80;
        float* s_dk   = smem;            // 80 x 56 (padded, 16B-aligned rows)
        float* s_tbox = smem + 4480;     // 80 x 12: lt0-2, rb0-2, vol, pad, pad, s0-2
        float* s_pk   = smem + 5440;     // 64 x 51

        if (tid < 80) {
            const float* tb6 = tgt_boxes + (size_t)(t0 + tid) * 6;
            float c0=tb6[0], c1=tb6[1], c2=tb6[2], s0=tb6[3], s1=tb6[4], s2=tb6[5];
            float l0=c0-0.5f*s0, l1=c1-0.5f*s1, l2=c2-0.5f*s2;
            float r0=c0+0.5f*s0, r1=c1+0.5f*s1, r2=c2+0.5f*s2;
            float* tw = s_tbox + tid*12;
            tw[0]=l0; tw[1]=l1; tw[2]=l2; tw[3]=r0; tw[4]=r1; tw[5]=r2;
            tw[6]=(r0-l0)*(r1-l1)*(r2-l2);
            tw[9]=s0; tw[10]=s1; tw[11]=s2;
        }
        __syncthreads();
        for (int e = tid; e < 80*K3; e += 1024) {
            int t = e / K3; int c = e - t*K3; int d = c % 3;
            float kp = tgt_kp[(size_t)t0*K3 + e];
            s_dk[t*56 + c] = (kp - s_tbox[t*12 + d]) / s_tbox[t*12 + 9 + d];
        }
        for (int e = tid; e < 64*K3; e += 1024)
            s_pk[e] = pred_kp[(size_t)p0*K3 + e];
        __syncthreads();

        const int pl = tid & 63, g = tid >> 6;
        float a[K3];
        #pragma unroll
        for (int c = 0; c < K3; ++c) a[c] = s_pk[pl*K3 + c];
        const int p = p0 + pl;
        const float* pb6 = pred_boxes + (size_t)p * 6;
        float pc0=pb6[0],pc1=pb6[1],pc2=pb6[2],ps0=pb6[3],ps1=pb6[4],ps2=pb6[5];
        float plt0=pc0-0.5f*ps0, plt1=pc1-0.5f*ps1, plt2=pc2-0.5f*ps2;
        float prb0=pc0+0.5f*ps0, prb1=pc1+0.5f*ps1, prb2=pc2+0.5f*ps2;
        float pvol=(prb0-plt0)*(prb1-plt1)*(prb2-plt2);

        #pragma unroll
        for (int k = 0; k < 5; ++k) {
            int tl = g*5 + k;                       // wave-uniform -> broadcast LDS reads
            const float* bbp = s_dk + tl*56;
            float sum = 0.f;
            #pragma unroll
            for (int c4 = 0; c4 < 12; ++c4) {       // ascending c, serial adds (order fixed)
                float4 q = *(const float4*)(bbp + 4*c4);
                sum += fabsf(a[4*c4+0] - q.x);
                sum += fabsf(a[4*c4+1] - q.y);
                sum += fabsf(a[4*c4+2] - q.z);
                sum += fabsf(a[4*c4+3] - q.w);
            }
            sum += fabsf(a[48] - bbp[48]);
            sum += fabsf(a[49] - bbp[49]);
            sum += fabsf(a[50] - bbp[50]);
            const float* tw = s_tbox + tl*12;
            float g_ = giou_cost(plt0,plt1,plt2,prb0,prb1,prb2,pvol,
                                 tw[0],tw[1],tw[2],tw[3],tw[4],tw[5],tw[6]);
            C[(size_t)p*NTGT + (t0+tl)] = sum - g_;
        }
        return;
    }

    // ================= LAP path: one block per batch =================
    const int b = bid;
    const int ln = tid & 63, w = tid >> 6;
    const int bq0 = b*NQ, bt0 = b*NT;
    float* tile = smem;                 // becomes [50][301] cost tile

    // stage tgt_kp slice into (future) tile area
    for (int e = tid; e < NT*K3; e += 1024)
        tile[e] = tgt_kp[(size_t)bt0*K3 + e];
    __syncthreads();

    // per-lane target row -> registers (every wave redundantly; lanes 0..49)
    float dk[K3];
    float tl0=0,tl1=0,tl2=0,tr0=0,tr1=0,tr2=0,tvol=0;
    if (ln < NT) {
        const float* tb6 = tgt_boxes + (size_t)(bt0+ln)*6;
        float c0=tb6[0],c1=tb6[1],c2=tb6[2],s0=tb6[3],s1=tb6[4],s2=tb6[5];
        tl0=c0-0.5f*s0; tl1=c1-0.5f*s1; tl2=c2-0.5f*s2;
        tr0=c0+0.5f*s0; tr1=c1+0.5f*s1; tr2=c2+0.5f*s2;
        tvol=(tr0-tl0)*(tr1-tl1)*(tr2-tl2);
        #pragma unroll
        for (int c = 0; c < K3; ++c) {
            int d = c % 3;
            float L = (d==0)?tl0:((d==1)?tl1:tl2);
            float S = (d==0)?s0:((d==1)?s1:s2);
            dk[c] = (tile[ln*K3 + c] - L) / S;
        }
    }
    __syncthreads();

    // build cost tile: wave w handles preds p = w, w+16, ... (bitwise same math as C path)
    for (int p = w; p < NQ; p += 16) {
        const float* prow = pred_kp + (size_t)(bq0+p)*K3;
        const float* pb6  = pred_boxes + (size_t)(bq0+p)*6;
        float pc0=pb6[0],pc1=pb6[1],pc2=pb6[2],ps0=pb6[3],ps1=pb6[4],ps2=pb6[5];
        float plt0=pc0-0.5f*ps0, plt1=pc1-0.5f*ps1, plt2=pc2-0.5f*ps2;
        float prb0=pc0+0.5f*ps0, prb1=pc1+0.5f*ps1, prb2=pc2+0.5f*ps2;
        float pvol=(prb0-plt0)*(prb1-plt1)*(prb2-plt2);
        if (ln < NT) {
            float sum = 0.f;
            #pragma unroll
            for (int c = 0; c < K3; ++c) sum += fabsf(prow[c] - dk[c]);
            float g_ = giou_cost(plt0,plt1,plt2,prb0,prb1,prb2,pvol,
                                 tl0,tl1,tl2,tr0,tr1,tr2,tvol);
            tile[ln*TSTRIDE + p] = sum - g_;
        }
    }
    __syncthreads();

    // ---- per-row argmin scan for greedy JV init (all 16 waves in parallel) ----
    float* s_rmv = smem + 15072;          // 50 floats: row min value
    int*   s_rmc = (int*)(smem + 15136);  // 50 ints:   row argmin column
    for (int r = w; r < NT; r += 16) {
        float bv = __builtin_inff(); int bj = 0x7fffffff;
        #pragma unroll
        for (int s = 0; s < 5; ++s) {
            int j = ln + 64*s;
            if (j < NQ) {
                float cv = tile[r*TSTRIDE + j];
                if (cv < bv || (cv == bv && j < bj)) { bv = cv; bj = j; }
            }
        }
        #pragma unroll
        for (int off = 32; off > 0; off >>= 1) {
            float ov = __shfl_xor(bv, off);
            int   oj = __shfl_xor(bj, off);
            if (ov < bv || (ov == bv && oj < bj)) { bv = ov; bj = oj; }
        }
        if (ln == 0) { s_rmv[r] = bv; s_rmc[r] = bj; }
    }
    __syncthreads();
    if (w != 0) return;                 // wave 0 continues alone; no more s_barrier

    // ---- register-resident JV shortest-augmenting-path (f32 labels/duals) ----
    // Greedy init: u[i] = min_j c[i][j], v = 0 (feasible dual, tight at row argmin);
    // assign each row its argmin column first-row-wins. Only contested rows need
    // Dijkstra, and they start from already-tight duals.
    // Column packing: lane ln owns columns j = 5*ln + s (s=0..4), lanes 0..59.
    // Ascending-j tie order == (lane asc, slot asc) -> 1-ballot argmin.
    float u = 0.0f;                     // dual for row ln (ln<50)
    int c4r = -1;                       // col4row[ln]
    if (ln < NT) u = s_rmv[ln];
    int wantj = (ln < NT) ? s_rmc[ln] : -1;
    for (int r = 0; r < NT; ++r) {
        int j = __builtin_amdgcn_readlane(wantj, r);
        unsigned long long taken = __ballot((ln < NT) && (c4r == j));
        if (taken == 0ull && ln == r) c4r = j;
    }

    float v5[5], sh[5];
    int pth[5];
    #pragma unroll
    for (int s = 0; s < 5; ++s) v5[s] = 0.0f;
    const float FINF = __builtin_inff();

    for (int curRow = 0; curRow < NT; ++curRow) {
        if (__builtin_amdgcn_readlane(c4r, curRow) >= 0) continue;  // greedy-assigned
        #pragma unroll
        for (int s = 0; s < 5; ++s) { sh[s] = FINF; pth[s] = -1; }
        int SCm = (ln < 60) ? 0 : 0x1F;            // lanes >=60 own no columns
        unsigned long long SRmask = 0ull;
        int i = curRow;
        float minVal = 0.0f;
        int sink = -1;

        while (true) {
            SRmask |= (1ull << i);
            float cf[5] = {0.f, 0.f, 0.f, 0.f, 0.f};
            if (ln < 60) {
                const float* rp = tile + i*TSTRIDE + 5*ln;   // contiguous 5 cols/lane
                cf[0]=rp[0]; cf[1]=rp[1]; cf[2]=rp[2]; cf[3]=rp[3]; cf[4]=rp[4];
            }
            float u_i = readlane_f32(u, i);        // i is wave-uniform -> v_readlane
            float e[5];
            #pragma unroll
            for (int s = 0; s < 5; ++s) {
                bool open = ((SCm >> s) & 1) == 0;
                float r = ((minVal + cf[s]) - u_i) - v5[s];  // reference op order (f32)
                bool upd = open && (r < sh[s]);
                sh[s]  = upd ? r : sh[s];
                pth[s] = upd ? i : pth[s];
                e[s] = open ? sh[s] : FINF;
            }
            float lmin = fminf(fminf(fminf(e[0], e[1]), fminf(e[2], e[3])), e[4]);
            int aslot = (e[0]==lmin) ? 0 : (e[1]==lmin) ? 1 :
                        (e[2]==lmin) ? 2 : (e[3]==lmin) ? 3 : 4;  // smallest s on tie
            // exact f32 argmin via strictly-monotonic u32 key; smallest lane = smallest j
            unsigned int kmin = wave_min_u32(f32key(lmin));
            unsigned long long cands = __ballot(f32key(lmin) == kmin);
            int lstar = __builtin_ctzll(cands);
            float m = readlane_f32(lmin, lstar);
            int jstar = 5*lstar + __builtin_amdgcn_readlane(aslot, lstar);
            minVal = m;
            // row4col[jstar] via col4row ballot (col4row constant during Dijkstra)
            unsigned long long mm = __ballot((ln < NT) && (c4r == jstar));
            // close column jstar
            if (ln == lstar) SCm |= 1 << (jstar - 5*lstar);
            if (mm == 0ull) { sink = jstar; break; }
            i = __builtin_ctzll(mm);
        }

        // ---- dual updates (pre-augment col4row) ----
        int cg  = (c4r >= 0) ? c4r : 0;
        int gow = cg / 5, gsl = cg - 5*gow;
        float g0 = __shfl(sh[0], gow);
        float g1 = __shfl(sh[1], gow);
        float g2 = __shfl(sh[2], gow);
        float g3 = __shfl(sh[3], gow);
        float g4 = __shfl(sh[4], gow);
        float gg = g0;
        gg = (gsl == 1) ? g1 : gg;
        gg = (gsl == 2) ? g2 : gg;
        gg = (gsl == 3) ? g3 : gg;
        gg = (gsl == 4) ? g4 : gg;
        bool inSR = (ln < NT) && ((SRmask >> ln) & 1ull);
        float du = (ln == curRow) ? minVal : (minVal - gg);
        u = inSR ? (u + du) : u;
        #pragma unroll
        for (int s = 0; s < 5; ++s) {
            bool closed = ((SCm >> s) & 1) != 0;
            v5[s] = closed ? (v5[s] - (minVal - sh[s])) : v5[s];
        }

        // ---- augment (uniform j/i chain -> readlane) ----
        int j = sink;
        while (true) {
            int ow2 = j / 5, sl2 = j - 5*ow2;
            int ps = pth[0];
            ps = (sl2==1) ? pth[1] : ps;
            ps = (sl2==2) ? pth[2] : ps;
            ps = (sl2==3) ? pth[3] : ps;
            ps = (sl2==4) ? pth[4] : ps;
            int ii = __builtin_amdgcn_readlane(ps, ow2);   // path[j]
            int jj = __builtin_amdgcn_readlane(c4r, ii);   // old col4row[ii]
            if (ln == ii) c4r = j;                          // col4row[ii] = j
            j = jj;
            if (ii == curRow) break;
        }
    }

    // ---- emit indices (argsort of matched pred indices) ----
    int* smem_i = (int*)smem;                       // tile is dead
    __threadfence_block();
    if (ln < NT) smem_i[ln] = c4r;
    __threadfence_block();
    int myc = c4r;
    int rank = 0;
    for (int s2 = 0; s2 < NT; ++s2) rank += (smem_i[s2] < myc) ? 1 : 0;
    if (ln < NT) {
        out_idx[b*(2*NT) + rank]      = (float)myc; // sorted pred (q) indices
        out_idx[b*(2*NT) + NT + rank] = (float)ln;  // matched tgt (t) indices
    }
}

extern "C" void kernel_launch(void* const* d_in, const int* in_sizes, int n_in,
                              void* d_out, int out_size, void* d_ws, size_t ws_size,
                              hipStream_t stream)
{
    const float* pred_kp    = (const float*)d_in[0];
    const float* pred_boxes = (const float*)d_in[1];
    const float* tgt_boxes  = (const float*)d_in[2];
    const float* tgt_kp     = (const float*)d_in[3];
    float* C   = (float*)d_out;
    float* idx = C + NC;
    // blocks 0..15: per-batch LAP (dispatched first); blocks 16..765: cost matrix
    fused_kernel<<<dim3(BSZ + 750), 1024, 0, stream>>>(
        pred_kp, pred_boxes, tgt_boxes, tgt_kp, C, idx);
}